// Round 5
// baseline (130.278 us; speedup 1.0000x reference)
//
#include <hip/hip_runtime.h>
#include <hip/hip_bf16.h>
#include <cstddef>

#define B_    128
#define D_    2048
#define C_    16522
#define BETA_INV 20.0f      // 1/0.05
#define LSTRIDE 16528       // padded logits row stride (floats)

#define NTILES 1033         // ceil(C/16)
#define NCHUNK 8
#define CHW    2066         // ceil(C/8)

typedef __bf16 bf16;
typedef bf16  bf16x8 __attribute__((ext_vector_type(8)));
typedef float f32x4  __attribute__((ext_vector_type(4)));

// ws layout (bytes):
//   logits : [0, 8462336)                128*16528*4
//   A_pack : [8462336, 8986624)          128*2048*2  bf16 fragment-ordered
//   part   : [8986624, 9052160)          128*8*16*4  row_loss partials
#define WS_APACK_OFF 8462336
#define WS_PART_OFF  8986624

// ---------------------------------------------------------------------------
// pack_a: inputs [128,2048] fp32 -> bf16 in MFMA A-fragment order.
// frag f = mtile*64 + kstep; element tid = f*64 + lane (bf16x8 each).
// A[m = mtile*16 + (lane&15)][k = kstep*32 + (lane>>4)*8 + j]
// ---------------------------------------------------------------------------
__global__ __launch_bounds__(256) void pack_a(const float* __restrict__ inp,
                                              bf16* __restrict__ ap) {
  const int tid  = blockIdx.x * 256 + threadIdx.x;   // 0..32767
  const int lane = tid & 63;
  const int ks   = (tid >> 6) & 63;
  const int mt   = tid >> 12;
  const int row  = mt * 16 + (lane & 15);
  const int col  = ks * 32 + (lane >> 4) * 8;
  const float4 v0 = *(const float4*)(inp + row * D_ + col);
  const float4 v1 = *(const float4*)(inp + row * D_ + col + 4);
  bf16x8 b;
  b[0] = (bf16)v0.x; b[1] = (bf16)v0.y; b[2] = (bf16)v0.z; b[3] = (bf16)v0.w;
  b[4] = (bf16)v1.x; b[5] = (bf16)v1.y; b[6] = (bf16)v1.z; b[7] = (bf16)v1.w;
  ((bf16x8*)ap)[tid] = b;
}

// ---------------------------------------------------------------------------
// copy_em: pure streaming memcpy em -> out_em.
// R5: NT store dropped — R4 measured this kernel at 2.6 TB/s while
// fillBufferAligned (plain stores) ran 6.9 TB/s of writes on the same
// device; NT's cache-bypass path is the prime suspect for throttling.
// Plain float4 stores = the m13-proven 6.3 TB/s pattern. 2x unroll issues
// two independent loads before the two stores for ILP. L3 write-allocate of
// out_em is acceptable: em+out_em ~ 270 MB vs 256 MB L3, so em stays
// mostly resident for the following gemm.
// ---------------------------------------------------------------------------
__global__ __launch_bounds__(256) void copy_em(const float* __restrict__ em,
                                               float* __restrict__ out_em) {
  const size_t n = (size_t)C_ * D_ / 4;          // 8,459,264 float4
  const size_t stride = (size_t)gridDim.x * 512;
  for (size_t i = (size_t)blockIdx.x * 512 + threadIdx.x; i < n; i += stride) {
    const f32x4 v0 = ((const f32x4*)em)[i];
    const bool  h1 = (i + 256) < n;
    f32x4 v1 = {};
    if (h1) v1 = ((const f32x4*)em)[i + 256];
    ((f32x4*)out_em)[i] = v0;
    if (h1) ((f32x4*)out_em)[i + 256] = v1;
  }
}

// ---------------------------------------------------------------------------
// gemm: 4 waves per block, one 16-row n-tile of em per block, in-block
// split-K (wave w owns k-steps [w*16, w*16+16)). Copy-through removed (R4) —
// no stores in the inner loop, so the per-step vmcnt wait only covers the
// L2 A-loads + the 1-deep em prefetch, and em is mostly L3-resident after
// copy_em. Writes only logits.
// ---------------------------------------------------------------------------
__global__ __launch_bounds__(256, 4) void gemm_logits(
    const bf16*  __restrict__ ap,
    const float* __restrict__ em,
    float*       __restrict__ logits)
{
  const int tid  = threadIdx.x;
  const int lane = tid & 63;
  const int w    = tid >> 6;          // K-quarter 0..3
  const int ml   = lane & 15;
  const int quad = lane >> 4;
  const int n0   = blockIdx.x * 16;
  const int r    = n0 + ml;
  const bool valid = r < C_;

  const float* bp = em + (size_t)(valid ? r : 0) * D_ + quad * 8;
  const bf16x8* af = (const bf16x8*)ap;

  const int ks0 = w * 16;

  f32x4 acc[8] = {};

  // prologue: em chunk for first iteration in flight
  f32x4 e0a = *(const f32x4*)(bp + ks0 * 32);
  f32x4 e0b = *(const f32x4*)(bp + ks0 * 32 + 4);

  #pragma unroll 3
  for (int i = 0; i < 15; ++i) {
    const int ks = ks0 + i;
    // A frags for THIS iteration (L2-resident)
    bf16x8 A0[8];
    #pragma unroll
    for (int mt = 0; mt < 8; ++mt)
      A0[mt] = af[(mt * 64 + ks) * 64 + lane];
    // em prefetch for NEXT iteration (L3-resident after copy_em)
    const f32x4 e1a = *(const f32x4*)(bp + (ks + 1) * 32);
    const f32x4 e1b = *(const f32x4*)(bp + (ks + 1) * 32 + 4);
    // consume
    bf16x8 bv;
    bv[0] = (bf16)e0a[0]; bv[1] = (bf16)e0a[1]; bv[2] = (bf16)e0a[2]; bv[3] = (bf16)e0a[3];
    bv[4] = (bf16)e0b[0]; bv[5] = (bf16)e0b[1]; bv[6] = (bf16)e0b[2]; bv[7] = (bf16)e0b[3];
    #pragma unroll
    for (int mt = 0; mt < 8; ++mt)
      acc[mt] = __builtin_amdgcn_mfma_f32_16x16x32_bf16(A0[mt], bv, acc[mt], 0, 0, 0);
    e0a = e1a; e0b = e1b;
  }
  // epilogue: iteration 15
  {
    const int ks = ks0 + 15;
    bf16x8 A0[8];
    #pragma unroll
    for (int mt = 0; mt < 8; ++mt)
      A0[mt] = af[(mt * 64 + ks) * 64 + lane];
    bf16x8 bv;
    bv[0] = (bf16)e0a[0]; bv[1] = (bf16)e0a[1]; bv[2] = (bf16)e0a[2]; bv[3] = (bf16)e0a[3];
    bv[4] = (bf16)e0b[0]; bv[5] = (bf16)e0b[1]; bv[6] = (bf16)e0b[2]; bv[7] = (bf16)e0b[3];
    #pragma unroll
    for (int mt = 0; mt < 8; ++mt)
      acc[mt] = __builtin_amdgcn_mfma_f32_16x16x32_bf16(A0[mt], bv, acc[mt], 0, 0, 0);
  }

  // combine the 4 K-partials through LDS; wave 0 writes logits
  __shared__ f32x4 red[3][8][64];     // 24 KB
  if (w > 0) {
    #pragma unroll
    for (int mt = 0; mt < 8; ++mt) red[w - 1][mt][lane] = acc[mt];
  }
  __syncthreads();
  if (w == 0 && valid) {
    #pragma unroll
    for (int mt = 0; mt < 8; ++mt) {
      f32x4 a = acc[mt];
      a += red[0][mt][lane];
      a += red[1][mt][lane];
      a += red[2][mt][lane];
      #pragma unroll
      for (int reg = 0; reg < 4; ++reg) {
        const int row = mt * 16 + quad * 4 + reg;
        logits[row * LSTRIDE + r] = a[reg] * BETA_INV;
      }
    }
  }
}

// ---------------------------------------------------------------------------
// row_loss phase A: grid = 128 rows x 8 chunks. Partial online-lse + top-6
// + label logit per chunk -> part[(b*8+c)*16].
// ---------------------------------------------------------------------------
__global__ __launch_bounds__(256) void row_loss_part(
    const float* __restrict__ logits,
    const int*   __restrict__ label,
    float*       __restrict__ part)
{
  const int b = blockIdx.x >> 3;
  const int c = blockIdx.x & 7;
  const int t = threadIdx.x;
  const int lo = c * CHW;
  const int hi = (lo + CHW < C_) ? lo + CHW : C_;
  const float* row = logits + b * LSTRIDE;
  const int y = label[b];

  float m = -INFINITY, s = 0.f, ly = -INFINITY;
  float tv[6]; int ti[6];
  #pragma unroll
  for (int q = 0; q < 6; ++q) { tv[q] = -INFINITY; ti[q] = -1; }

  for (int i = lo + t; i < hi; i += 256) {
    const float v = row[i];
    if (v > m) { s = s * __expf(m - v) + 1.f; m = v; }
    else       { s += __expf(v - m); }
    if (i == y) ly = v;
    if (v > tv[5]) {
      tv[5] = v; ti[5] = i;
      #pragma unroll
      for (int q = 5; q > 0; --q)
        if (tv[q] > tv[q - 1]) {
          const float fv = tv[q]; tv[q] = tv[q - 1]; tv[q - 1] = fv;
          const int   fi = ti[q]; ti[q] = ti[q - 1]; ti[q - 1] = fi;
        }
    }
  }

  __shared__ float rm[256], rs[256];
  __shared__ float cv[1536];
  __shared__ int   ci[1536];
  __shared__ float sly;

  rm[t] = m; rs[t] = s;
  #pragma unroll
  for (int q = 0; q < 6; ++q) { cv[t * 6 + q] = tv[q]; ci[t * 6 + q] = ti[q]; }
  if (t == 0) sly = -INFINITY;
  __syncthreads();
  if (ly != -INFINITY) sly = ly;

  for (int off = 128; off >= 1; off >>= 1) {
    if (t < off) {
      const float m2 = rm[t + off], s2 = rs[t + off];
      const float M = fmaxf(rm[t], m2);
      rs[t] = rs[t] * __expf(rm[t] - M) + s2 * __expf(m2 - M);
      rm[t] = M;
    }
    __syncthreads();
  }

  if (t < 64) {   // wave 0: top-6 of 1536 candidates
    float otv[6]; int oti[6];
    for (int rr = 0; rr < 6; ++rr) {
      float bv = -INFINITY; int bi = -1, bs = -1;
      for (int u = 0; u < 24; ++u) {
        const int slot = t * 24 + u;
        const float v = cv[slot];
        if (v > bv) { bv = v; bi = ci[slot]; bs = slot; }
      }
      #pragma unroll
      for (int off = 32; off >= 1; off >>= 1) {
        const float ov = __shfl_down(bv, off);
        const int   oi = __shfl_down(bi, off);
        const int   os = __shfl_down(bs, off);
        if (ov > bv) { bv = ov; bi = oi; bs = os; }
      }
      bv = __shfl(bv, 0); bi = __shfl(bi, 0); bs = __shfl(bs, 0);
      if (bs >= t * 24 && bs < (t + 1) * 24) cv[bs] = -INFINITY;
      otv[rr] = bv; oti[rr] = bi;
    }
    if (t == 0) {
      float* p = part + (size_t)(b * 8 + c) * 16;
      p[0] = rm[0]; p[1] = rs[0]; p[2] = sly;
      #pragma unroll
      for (int q = 0; q < 6; ++q) { p[4 + q] = otv[q]; ((int*)p)[10 + q] = oti[q]; }
    }
  }
}

// ---------------------------------------------------------------------------
// row_loss merge: 128 blocks x 64 threads. Merge 8 chunk-partials, compute
// loss, atomicAdd into out[0].
// ---------------------------------------------------------------------------
__global__ __launch_bounds__(64) void row_loss_merge(
    const float* __restrict__ part,
    const int*   __restrict__ label,
    float*       __restrict__ out)
{
  const int b = blockIdx.x;
  const int lane = threadIdx.x;
  const int y = label[b];

  float m = -INFINITY, s = 0.f, ly = -INFINITY;
  if (lane < 8) {
    const float* p = part + (size_t)(b * 8 + lane) * 16;
    m = p[0]; s = p[1]; ly = p[2];
  }
  float M = m, LY = ly;
  #pragma unroll
  for (int off = 32; off >= 1; off >>= 1) {
    M  = fmaxf(M,  __shfl_down(M,  off));
    LY = fmaxf(LY, __shfl_down(LY, off));
  }
  M = __shfl(M, 0); LY = __shfl(LY, 0);
  float contrib = (lane < 8) ? s * __expf(m - M) : 0.f;
  #pragma unroll
  for (int off = 32; off >= 1; off >>= 1) contrib += __shfl_down(contrib, off);
  const float S = __shfl(contrib, 0);

  float v = -INFINITY; int idx = -1;
  if (lane < 48) {
    const float* p = part + (size_t)(b * 8 + lane / 6) * 16;
    v   = p[4 + lane % 6];
    idx = ((const int*)p)[10 + lane % 6];
  }
  float stop = 0.f; int intop = 0;
  for (int rr = 0; rr < 6; ++rr) {
    float bv = v; int bi = idx, bl = lane;
    #pragma unroll
    for (int off = 32; off >= 1; off >>= 1) {
      const float ov = __shfl_down(bv, off);
      const int   oi = __shfl_down(bi, off);
      const int   ol = __shfl_down(bl, off);
      if (ov > bv) { bv = ov; bi = oi; bl = ol; }
    }
    bv = __shfl(bv, 0); bi = __shfl(bi, 0); bl = __shfl(bl, 0);
    stop += bv;
    if (bi == y) intop = 1;
    if (lane == bl) v = -INFINITY;
  }

  if (lane == 0) {
    const float lse = M + logf(S);
    const float loss = intop ? (13.f * lse - LY - 2.f * stop)
                             : (15.f * lse - 3.f * LY - 2.f * stop);
    atomicAdd(out, loss * (1.0f / 128.0f));
  }
}

// ---------------------------------------------------------------------------
// em_update: labels staged to LDS. Block i acts only if i is the first
// occurrence of label[i]; walks the duplicate chain sequentially (exact fp32).
// ---------------------------------------------------------------------------
__global__ __launch_bounds__(256) void em_update(
    const float* __restrict__ inp,
    const int*   __restrict__ label,
    const float* __restrict__ em,
    const int*   __restrict__ epoch,
    float*       __restrict__ out_em)
{
  __shared__ int lbl[B_];
  __shared__ float red[4];
  const int t = threadIdx.x;
  if (t < B_) lbl[t] = label[t];
  __syncthreads();

  const int i = blockIdx.x;
  const int y = lbl[i];
  for (int j = 0; j < i; ++j)
    if (lbl[j] == y) return;            // uniform: all threads agree

  const float alpha = 0.01f * (float)epoch[0];
  const int lane = t & 63, wave = t >> 6;

  float r[8];
  #pragma unroll
  for (int u = 0; u < 8; ++u) r[u] = em[(size_t)y * D_ + t + u * 256];

  for (int j = i; j < B_; ++j) {
    if (lbl[j] != y) continue;          // uniform branch
    const float* x = inp + j * D_;
    float ss = 0.f;
    #pragma unroll
    for (int u = 0; u < 8; ++u) {
      r[u] = alpha * r[u] + (1.f - alpha) * x[t + u * 256];
      ss += r[u] * r[u];
    }
    #pragma unroll
    for (int off = 32; off >= 1; off >>= 1) ss += __shfl_down(ss, off);
    if (lane == 0) red[wave] = ss;
    __syncthreads();
    const float inv = 1.f / sqrtf(red[0] + red[1] + red[2] + red[3]);
    #pragma unroll
    for (int u = 0; u < 8; ++u) r[u] *= inv;
    __syncthreads();                    // red[] reused next chain step
  }

  #pragma unroll
  for (int u = 0; u < 8; ++u) out_em[(size_t)y * D_ + t + u * 256] = r[u];
}

// ---------------------------------------------------------------------------
extern "C" void kernel_launch(void* const* d_in, const int* in_sizes, int n_in,
                              void* d_out, int out_size, void* d_ws, size_t ws_size,
                              hipStream_t stream) {
  const float* inp   = (const float*)d_in[0];
  const int*   label = (const int*)d_in[1];
  const float* em    = (const float*)d_in[2];
  const int*   epoch = (const int*)d_in[3];

  float* out    = (float*)d_out;
  float* out_em = out + 1;
  float* logits = (float*)d_ws;
  bf16*  apack  = (bf16*)((char*)d_ws + WS_APACK_OFF);
  float* part   = (float*)((char*)d_ws + WS_PART_OFF);

  hipMemsetAsync(d_out, 0, sizeof(float), stream);   // zero the loss slot

  pack_a        <<<dim3(128),        dim3(256), 0, stream>>>(inp, apack);
  copy_em       <<<dim3(2048),       dim3(256), 0, stream>>>(em, out_em);
  gemm_logits   <<<dim3(NTILES),     dim3(256), 0, stream>>>(apack, em, logits);
  row_loss_part <<<dim3(B_ * NCHUNK),dim3(256), 0, stream>>>(logits, label, part);
  row_loss_merge<<<dim3(B_),         dim3(64),  0, stream>>>(part, label, out);
  em_update     <<<dim3(B_),         dim3(256), 0, stream>>>(inp, label, em, epoch, out_em);
}

// Round 6
// 128.803 us; speedup vs baseline: 1.0115x; 1.0115x over previous
//
#include <hip/hip_runtime.h>
#include <hip/hip_bf16.h>
#include <cstddef>

#define B_    128
#define D_    2048
#define C_    16522
#define BETA_INV 20.0f      // 1/0.05
#define LSTRIDE 16528       // padded logits row stride (floats)

#define NTILES 1033         // ceil(C/16)
#define NCHUNK 8
#define CHW    2066         // ceil(C/8)

typedef __bf16 bf16;
typedef bf16  bf16x8 __attribute__((ext_vector_type(8)));
typedef float f32x4  __attribute__((ext_vector_type(4)));

// ws layout (bytes):
//   logits : [0, 8462336)                128*16528*4
//   A_pack : [8462336, 8986624)          128*2048*2  bf16 fragment-ordered
//   part   : [8986624, 9052160)          128*8*16*4  row_loss partials
#define WS_APACK_OFF 8462336
#define WS_PART_OFF  8986624

// ---------------------------------------------------------------------------
// pack_a: inputs [128,2048] fp32 -> bf16 in MFMA A-fragment order.
// frag f = mtile*64 + kstep; element tid = f*64 + lane (bf16x8 each).
// A[m = mtile*16 + (lane&15)][k = kstep*32 + (lane>>4)*8 + j]
// ---------------------------------------------------------------------------
__global__ __launch_bounds__(256) void pack_a(const float* __restrict__ inp,
                                              bf16* __restrict__ ap) {
  const int tid  = blockIdx.x * 256 + threadIdx.x;   // 0..32767
  const int lane = tid & 63;
  const int ks   = (tid >> 6) & 63;
  const int mt   = tid >> 12;
  const int row  = mt * 16 + (lane & 15);
  const int col  = ks * 32 + (lane >> 4) * 8;
  const float4 v0 = *(const float4*)(inp + row * D_ + col);
  const float4 v1 = *(const float4*)(inp + row * D_ + col + 4);
  bf16x8 b;
  b[0] = (bf16)v0.x; b[1] = (bf16)v0.y; b[2] = (bf16)v0.z; b[3] = (bf16)v0.w;
  b[4] = (bf16)v1.x; b[5] = (bf16)v1.y; b[6] = (bf16)v1.z; b[7] = (bf16)v1.w;
  ((bf16x8*)ap)[tid] = b;
}

// ---------------------------------------------------------------------------
// copy_em: streaming memcpy em -> out_em.
// R6: ALIGNMENT fix. out_em = d_out + 4 bytes, so every f32x4 store in all
// prior variants was at addr % 16 == 4 (hardware-split stores) — the 2.6
// TB/s plateau (vs fillBuffer's 6.9 TB/s aligned writes, m13's 6.3 TB/s
// aligned copy). NT made it worse (partial-sector HBM writes, +50% WRITE).
// Fix: store group k = out-floats [3+4k, 7+4k) -> base+3 floats is 16B-
// aligned. Source em floats [3+4k, 7+4k) from lane's own aligned load
// (elem 3) + neighbor lane's (elems 0..2) via __shfl_down; lane 63 and the
// loop-edge lane load eg[k+1] directly. Loads stay fully aligned.
// Peel: out_em[0..2] and out_em[N-1] scalar (4B stores are aligned).
// ---------------------------------------------------------------------------
__global__ __launch_bounds__(256) void copy_em(const float* __restrict__ em,
                                               float* __restrict__ out_em) {
  const size_t N = (size_t)C_ * D_;            // 33,837,056 floats
  const size_t G = (N - 4) / 4;                // 8,459,263 aligned store groups
  const f32x4* eg = (const f32x4*)em;
  const size_t stride = (size_t)gridDim.x * 256;
  const int lane = threadIdx.x & 63;

  for (size_t k0 = (size_t)blockIdx.x * 256; k0 < G; k0 += stride) {
    const size_t k = k0 + threadIdx.x;
    const bool act = k < G;
    f32x4 v = {};
    if (act) v = eg[k];
    f32x4 nb;
    nb[0] = __shfl_down(v[0], 1);
    nb[1] = __shfl_down(v[1], 1);
    nb[2] = __shfl_down(v[2], 1);
    if (act && (lane == 63 || k == G - 1)) {   // neighbor lane absent
      const f32x4 x = eg[k + 1];               // k+1 <= G = last em group
      nb[0] = x[0]; nb[1] = x[1]; nb[2] = x[2];
    }
    if (act) {
      f32x4 o;
      o[0] = v[3]; o[1] = nb[0]; o[2] = nb[1]; o[3] = nb[2];
      *(f32x4*)(out_em + 3 + 4 * k) = o;       // 16B-aligned store
    }
  }

  if (blockIdx.x == 0 && threadIdx.x < 3)
    out_em[threadIdx.x] = em[threadIdx.x];
  if (blockIdx.x == 0 && threadIdx.x == 3)
    out_em[N - 1] = em[N - 1];
}

// ---------------------------------------------------------------------------
// gemm: 4 waves per block, one 16-row n-tile of em per block, in-block
// split-K (wave w owns k-steps [w*16, w*16+16)). Copy-through removed (R4) —
// no stores in the inner loop, so the per-step vmcnt wait only covers the
// L2 A-loads + the 1-deep em prefetch, and em is mostly L3-resident after
// copy_em. Writes only logits.
// ---------------------------------------------------------------------------
__global__ __launch_bounds__(256, 4) void gemm_logits(
    const bf16*  __restrict__ ap,
    const float* __restrict__ em,
    float*       __restrict__ logits)
{
  const int tid  = threadIdx.x;
  const int lane = tid & 63;
  const int w    = tid >> 6;          // K-quarter 0..3
  const int ml   = lane & 15;
  const int quad = lane >> 4;
  const int n0   = blockIdx.x * 16;
  const int r    = n0 + ml;
  const bool valid = r < C_;

  const float* bp = em + (size_t)(valid ? r : 0) * D_ + quad * 8;
  const bf16x8* af = (const bf16x8*)ap;

  const int ks0 = w * 16;

  f32x4 acc[8] = {};

  // prologue: em chunk for first iteration in flight
  f32x4 e0a = *(const f32x4*)(bp + ks0 * 32);
  f32x4 e0b = *(const f32x4*)(bp + ks0 * 32 + 4);

  #pragma unroll 3
  for (int i = 0; i < 15; ++i) {
    const int ks = ks0 + i;
    // A frags for THIS iteration (L2-resident)
    bf16x8 A0[8];
    #pragma unroll
    for (int mt = 0; mt < 8; ++mt)
      A0[mt] = af[(mt * 64 + ks) * 64 + lane];
    // em prefetch for NEXT iteration (L3-resident after copy_em)
    const f32x4 e1a = *(const f32x4*)(bp + (ks + 1) * 32);
    const f32x4 e1b = *(const f32x4*)(bp + (ks + 1) * 32 + 4);
    // consume
    bf16x8 bv;
    bv[0] = (bf16)e0a[0]; bv[1] = (bf16)e0a[1]; bv[2] = (bf16)e0a[2]; bv[3] = (bf16)e0a[3];
    bv[4] = (bf16)e0b[0]; bv[5] = (bf16)e0b[1]; bv[6] = (bf16)e0b[2]; bv[7] = (bf16)e0b[3];
    #pragma unroll
    for (int mt = 0; mt < 8; ++mt)
      acc[mt] = __builtin_amdgcn_mfma_f32_16x16x32_bf16(A0[mt], bv, acc[mt], 0, 0, 0);
    e0a = e1a; e0b = e1b;
  }
  // epilogue: iteration 15
  {
    const int ks = ks0 + 15;
    bf16x8 A0[8];
    #pragma unroll
    for (int mt = 0; mt < 8; ++mt)
      A0[mt] = af[(mt * 64 + ks) * 64 + lane];
    bf16x8 bv;
    bv[0] = (bf16)e0a[0]; bv[1] = (bf16)e0a[1]; bv[2] = (bf16)e0a[2]; bv[3] = (bf16)e0a[3];
    bv[4] = (bf16)e0b[0]; bv[5] = (bf16)e0b[1]; bv[6] = (bf16)e0b[2]; bv[7] = (bf16)e0b[3];
    #pragma unroll
    for (int mt = 0; mt < 8; ++mt)
      acc[mt] = __builtin_amdgcn_mfma_f32_16x16x32_bf16(A0[mt], bv, acc[mt], 0, 0, 0);
  }

  // combine the 4 K-partials through LDS; wave 0 writes logits
  __shared__ f32x4 red[3][8][64];     // 24 KB
  if (w > 0) {
    #pragma unroll
    for (int mt = 0; mt < 8; ++mt) red[w - 1][mt][lane] = acc[mt];
  }
  __syncthreads();
  if (w == 0 && valid) {
    #pragma unroll
    for (int mt = 0; mt < 8; ++mt) {
      f32x4 a = acc[mt];
      a += red[0][mt][lane];
      a += red[1][mt][lane];
      a += red[2][mt][lane];
      #pragma unroll
      for (int reg = 0; reg < 4; ++reg) {
        const int row = mt * 16 + quad * 4 + reg;
        logits[row * LSTRIDE + r] = a[reg] * BETA_INV;
      }
    }
  }
}

// ---------------------------------------------------------------------------
// row_loss phase A: grid = 128 rows x 8 chunks. Partial online-lse + top-6
// + label logit per chunk -> part[(b*8+c)*16].
// ---------------------------------------------------------------------------
__global__ __launch_bounds__(256) void row_loss_part(
    const float* __restrict__ logits,
    const int*   __restrict__ label,
    float*       __restrict__ part)
{
  const int b = blockIdx.x >> 3;
  const int c = blockIdx.x & 7;
  const int t = threadIdx.x;
  const int lo = c * CHW;
  const int hi = (lo + CHW < C_) ? lo + CHW : C_;
  const float* row = logits + b * LSTRIDE;
  const int y = label[b];

  float m = -INFINITY, s = 0.f, ly = -INFINITY;
  float tv[6]; int ti[6];
  #pragma unroll
  for (int q = 0; q < 6; ++q) { tv[q] = -INFINITY; ti[q] = -1; }

  for (int i = lo + t; i < hi; i += 256) {
    const float v = row[i];
    if (v > m) { s = s * __expf(m - v) + 1.f; m = v; }
    else       { s += __expf(v - m); }
    if (i == y) ly = v;
    if (v > tv[5]) {
      tv[5] = v; ti[5] = i;
      #pragma unroll
      for (int q = 5; q > 0; --q)
        if (tv[q] > tv[q - 1]) {
          const float fv = tv[q]; tv[q] = tv[q - 1]; tv[q - 1] = fv;
          const int   fi = ti[q]; ti[q] = ti[q - 1]; ti[q - 1] = fi;
        }
    }
  }

  __shared__ float rm[256], rs[256];
  __shared__ float cv[1536];
  __shared__ int   ci[1536];
  __shared__ float sly;

  rm[t] = m; rs[t] = s;
  #pragma unroll
  for (int q = 0; q < 6; ++q) { cv[t * 6 + q] = tv[q]; ci[t * 6 + q] = ti[q]; }
  if (t == 0) sly = -INFINITY;
  __syncthreads();
  if (ly != -INFINITY) sly = ly;

  for (int off = 128; off >= 1; off >>= 1) {
    if (t < off) {
      const float m2 = rm[t + off], s2 = rs[t + off];
      const float M = fmaxf(rm[t], m2);
      rs[t] = rs[t] * __expf(rm[t] - M) + s2 * __expf(m2 - M);
      rm[t] = M;
    }
    __syncthreads();
  }

  if (t < 64) {   // wave 0: top-6 of 1536 candidates
    float otv[6]; int oti[6];
    for (int rr = 0; rr < 6; ++rr) {
      float bv = -INFINITY; int bi = -1, bs = -1;
      for (int u = 0; u < 24; ++u) {
        const int slot = t * 24 + u;
        const float v = cv[slot];
        if (v > bv) { bv = v; bi = ci[slot]; bs = slot; }
      }
      #pragma unroll
      for (int off = 32; off >= 1; off >>= 1) {
        const float ov = __shfl_down(bv, off);
        const int   oi = __shfl_down(bi, off);
        const int   os = __shfl_down(bs, off);
        if (ov > bv) { bv = ov; bi = oi; bs = os; }
      }
      bv = __shfl(bv, 0); bi = __shfl(bi, 0); bs = __shfl(bs, 0);
      if (bs >= t * 24 && bs < (t + 1) * 24) cv[bs] = -INFINITY;
      otv[rr] = bv; oti[rr] = bi;
    }
    if (t == 0) {
      float* p = part + (size_t)(b * 8 + c) * 16;
      p[0] = rm[0]; p[1] = rs[0]; p[2] = sly;
      #pragma unroll
      for (int q = 0; q < 6; ++q) { p[4 + q] = otv[q]; ((int*)p)[10 + q] = oti[q]; }
    }
  }
}

// ---------------------------------------------------------------------------
// row_loss merge: 128 blocks x 64 threads. Merge 8 chunk-partials, compute
// loss, atomicAdd into out[0].
// ---------------------------------------------------------------------------
__global__ __launch_bounds__(64) void row_loss_merge(
    const float* __restrict__ part,
    const int*   __restrict__ label,
    float*       __restrict__ out)
{
  const int b = blockIdx.x;
  const int lane = threadIdx.x;
  const int y = label[b];

  float m = -INFINITY, s = 0.f, ly = -INFINITY;
  if (lane < 8) {
    const float* p = part + (size_t)(b * 8 + lane) * 16;
    m = p[0]; s = p[1]; ly = p[2];
  }
  float M = m, LY = ly;
  #pragma unroll
  for (int off = 32; off >= 1; off >>= 1) {
    M  = fmaxf(M,  __shfl_down(M,  off));
    LY = fmaxf(LY, __shfl_down(LY, off));
  }
  M = __shfl(M, 0); LY = __shfl(LY, 0);
  float contrib = (lane < 8) ? s * __expf(m - M) : 0.f;
  #pragma unroll
  for (int off = 32; off >= 1; off >>= 1) contrib += __shfl_down(contrib, off);
  const float S = __shfl(contrib, 0);

  float v = -INFINITY; int idx = -1;
  if (lane < 48) {
    const float* p = part + (size_t)(b * 8 + lane / 6) * 16;
    v   = p[4 + lane % 6];
    idx = ((const int*)p)[10 + lane % 6];
  }
  float stop = 0.f; int intop = 0;
  for (int rr = 0; rr < 6; ++rr) {
    float bv = v; int bi = idx, bl = lane;
    #pragma unroll
    for (int off = 32; off >= 1; off >>= 1) {
      const float ov = __shfl_down(bv, off);
      const int   oi = __shfl_down(bi, off);
      const int   ol = __shfl_down(bl, off);
      if (ov > bv) { bv = ov; bi = oi; bl = ol; }
    }
    bv = __shfl(bv, 0); bi = __shfl(bi, 0); bl = __shfl(bl, 0);
    stop += bv;
    if (bi == y) intop = 1;
    if (lane == bl) v = -INFINITY;
  }

  if (lane == 0) {
    const float lse = M + logf(S);
    const float loss = intop ? (13.f * lse - LY - 2.f * stop)
                             : (15.f * lse - 3.f * LY - 2.f * stop);
    atomicAdd(out, loss * (1.0f / 128.0f));
  }
}

// ---------------------------------------------------------------------------
// em_update: labels staged to LDS. Block i acts only if i is the first
// occurrence of label[i]; walks the duplicate chain sequentially (exact fp32).
// (Scalar 4B stores to out_em rows — alignment not an issue here.)
// ---------------------------------------------------------------------------
__global__ __launch_bounds__(256) void em_update(
    const float* __restrict__ inp,
    const int*   __restrict__ label,
    const float* __restrict__ em,
    const int*   __restrict__ epoch,
    float*       __restrict__ out_em)
{
  __shared__ int lbl[B_];
  __shared__ float red[4];
  const int t = threadIdx.x;
  if (t < B_) lbl[t] = label[t];
  __syncthreads();

  const int i = blockIdx.x;
  const int y = lbl[i];
  for (int j = 0; j < i; ++j)
    if (lbl[j] == y) return;            // uniform: all threads agree

  const float alpha = 0.01f * (float)epoch[0];
  const int lane = t & 63, wave = t >> 6;

  float r[8];
  #pragma unroll
  for (int u = 0; u < 8; ++u) r[u] = em[(size_t)y * D_ + t + u * 256];

  for (int j = i; j < B_; ++j) {
    if (lbl[j] != y) continue;          // uniform branch
    const float* x = inp + j * D_;
    float ss = 0.f;
    #pragma unroll
    for (int u = 0; u < 8; ++u) {
      r[u] = alpha * r[u] + (1.f - alpha) * x[t + u * 256];
      ss += r[u] * r[u];
    }
    #pragma unroll
    for (int off = 32; off >= 1; off >>= 1) ss += __shfl_down(ss, off);
    if (lane == 0) red[wave] = ss;
    __syncthreads();
    const float inv = 1.f / sqrtf(red[0] + red[1] + red[2] + red[3]);
    #pragma unroll
    for (int u = 0; u < 8; ++u) r[u] *= inv;
    __syncthreads();                    // red[] reused next chain step
  }

  #pragma unroll
  for (int u = 0; u < 8; ++u) out_em[(size_t)y * D_ + t + u * 256] = r[u];
}

// ---------------------------------------------------------------------------
extern "C" void kernel_launch(void* const* d_in, const int* in_sizes, int n_in,
                              void* d_out, int out_size, void* d_ws, size_t ws_size,
                              hipStream_t stream) {
  const float* inp   = (const float*)d_in[0];
  const int*   label = (const int*)d_in[1];
  const float* em    = (const float*)d_in[2];
  const int*   epoch = (const int*)d_in[3];

  float* out    = (float*)d_out;
  float* out_em = out + 1;
  float* logits = (float*)d_ws;
  bf16*  apack  = (bf16*)((char*)d_ws + WS_APACK_OFF);
  float* part   = (float*)((char*)d_ws + WS_PART_OFF);

  hipMemsetAsync(d_out, 0, sizeof(float), stream);   // zero the loss slot

  pack_a        <<<dim3(128),        dim3(256), 0, stream>>>(inp, apack);
  copy_em       <<<dim3(2048),       dim3(256), 0, stream>>>(em, out_em);
  gemm_logits   <<<dim3(NTILES),     dim3(256), 0, stream>>>(apack, em, logits);
  row_loss_part <<<dim3(B_ * NCHUNK),dim3(256), 0, stream>>>(logits, label, part);
  row_loss_merge<<<dim3(B_),         dim3(64),  0, stream>>>(part, label, out);
  em_update     <<<dim3(B_),         dim3(256), 0, stream>>>(inp, label, em, epoch, out_em);
}